// Round 11
// baseline (1022.155 us; speedup 1.0000x reference)
//
#include <hip/hip_runtime.h>
#include <hip/hip_bf16.h>
#include <hip/hip_cooperative_groups.h>

namespace cg = cooperative_groups;

#define DFEAT 128

typedef _Float16 h2 __attribute__((ext_vector_type(2)));
typedef _Float16 f16x8 __attribute__((ext_vector_type(8)));
typedef float f32x4  __attribute__((ext_vector_type(4)));
typedef unsigned short u16x8 __attribute__((ext_vector_type(8)));

__device__ __forceinline__ unsigned short f16b(float f) {
    _Float16 hf = (_Float16)f;
    unsigned short b; __builtin_memcpy(&b, &hf, 2);
    return b;
}
__device__ __forceinline__ unsigned pack_f16(float lo, float hi) {
    return (unsigned)f16b(lo) | ((unsigned)f16b(hi) << 16);
}
__device__ __forceinline__ float h2f(h2 v) { float f; __builtin_memcpy(&f, &v, 4); return f; }
__device__ __forceinline__ h2 f2h(float f) { h2 v; __builtin_memcpy(&v, &f, 4); return v; }

// Chebyshev algebra folded into weights (fp32, at prep):
//   out = h@(W0 - W2) + Tx1@W1 + P@(2*W2),  P = L_hat @ Tx1
// -> both props are identical pure gathers.
//
// Round-10 conclusions: (a) the unsliced gather (~37us, 91MB at ~2.5 TB/s of
// random 64B lines = per-XCD compulsory table replication) is at the fabric
// random-access service floor -- every locality/geometry variant loses;
// (b) ~90-100us of the runtime is 13 inter-dispatch gaps (~8us each).
// Round-11: fuse the 5 preproc dispatches (streaming, no serial gather
// chains -> coop-safe, phases verified correct in r9) into ONE cooperative
// kernel; keep the proven r8 props/GEMMs untouched (props need 1 node/wave
// with 50K-wave oversubscription, which coop co-residency cannot provide).

// ---------------- cooperative preprocessing mega-kernel ----------------
// P0 zero deg8 + pack x->f16 + fold W   | P1 degree count
// P2 64-chunk scan -> poff,dinv,partial | P3 1-wave csum scan
// P4 final row_ptr                      | P5 CSR fill
__global__ __launch_bounds__(256, 8) void prep_mega_kernel(
    const float2* __restrict__ x2, const int* __restrict__ ei,
    const float* __restrict__ W1, const float* __restrict__ W2,
    const float* __restrict__ W3,
    unsigned* __restrict__ xb, unsigned short* __restrict__ wt,
    int* __restrict__ deg8, int* __restrict__ poff,
    int* __restrict__ row_ptr, float* __restrict__ dinv,
    unsigned* __restrict__ e_cw, int* __restrict__ csum,
    int N, int E)
{
    cg::grid_group grid = cg::this_grid();
    const int t = threadIdx.x;
    const int tid = blockIdx.x * 256 + t;
    const int nthreads = gridDim.x * 256;
    const int lane = t & 63;

    // ---- P0: zero deg8 + pack x -> f16 + fold W -> transposed f16 ----
    const int NPK = N * (DFEAT / 2);
    for (int i = tid; i < 8 * N; i += nthreads) deg8[i] = 0;
    for (int i = tid; i < NPK; i += nthreads) {
        float2 v = x2[i];
        xb[i] = pack_f16(v.x, v.y);
    }
    const int PER = 3 * DFEAT * DFEAT;
    for (int i = tid; i < 3 * PER; i += nthreads) {
        int layer = i / PER;
        int rem = i - layer * PER;
        const float* W = (layer == 0) ? W1 : ((layer == 1) ? W2 : W3);
        int seg = rem >> 14;
        int k   = (rem >> 7) & 127;
        int nn  = rem & 127;
        float w = W[rem];
        if (seg == 0) w -= W[rem + 2 * DFEAT * DFEAT];   // W0' = W0 - W2
        else if (seg == 2) w *= 2.f;                      // W2' = 2*W2
        wt[layer * PER + (seg << 14) + (nn << 7) + k] = f16b(w);
    }
    grid.sync();

    // ---- P1: degree count (edge-index-partitioned atomics) ----
    for (int e = tid; e < E; e += nthreads) {
        int r = ei[e];
        int c = ei[E + e];
        if (r != c) atomicAdd(&deg8[((e >> 8) & 7) * N + r], 1);
    }
    grid.sync();

    // ---- P2: per-64-node chunks: poff, dinv, chunk-local scan, chunk totals ----
    const int NCH = (N + 63) / 64;
    const int gwave = tid >> 6;
    const int ngwave = nthreads >> 6;
    for (int w = gwave; w < NCH; w += ngwave) {
        int node = w * 64 + lane;
        int tot = 0;
        if (node < N) {
            int run = 0;
            #pragma unroll
            for (int p = 0; p < 8; ++p) {
                int d = deg8[p * N + node];
                poff[p * N + node] = run;   // partition start; doubles as fill cursor
                run += d;
            }
            tot = run;
            dinv[node] = (tot > 0) ? rsqrtf((float)tot) : 0.f;
        }
        int vi = tot;
        #pragma unroll
        for (int off = 1; off < 64; off <<= 1) {
            int xx = __shfl_up(vi, off);
            if (lane >= off) vi += xx;
        }
        if (node < N) row_ptr[node + 1] = vi;   // chunk-local inclusive prefix
        if (lane == 63) csum[w] = vi;           // chunk total
    }
    grid.sync();

    // ---- P3: exclusive scan of chunk totals (one wave) ----
    if (blockIdx.x == 0 && t < 64) {
        int carry = 0;
        for (int base = 0; base < NCH; base += 64) {
            int v = (base + t < NCH) ? csum[base + t] : 0;
            int vi = v;
            #pragma unroll
            for (int off = 1; off < 64; off <<= 1) {
                int xx = __shfl_up(vi, off);
                if (t >= off) vi += xx;
            }
            if (base + t < NCH) csum[base + t] = carry + vi - v;
            carry += __shfl(vi, 63);
        }
    }
    grid.sync();

    // ---- P4: add chunk offsets -> final row_ptr ----
    for (int i = tid; i < N; i += nthreads) {
        if (i == 0) row_ptr[0] = 0;
        row_ptr[i + 1] += csum[i >> 6];
    }
    grid.sync();

    // ---- P5: CSR fill (col:u16 | w:f16) ----
    for (int e = tid; e < E; e += nthreads) {
        int r = ei[e];
        int c = ei[E + e];
        if (r != c) {
            int p = (e >> 8) & 7;   // must match P1 partitioning
            int k = atomicAdd(&poff[p * N + r], 1);
            int pos = row_ptr[r] + k;
            float w = -dinv[r] * dinv[c];
            e_cw[pos] = (unsigned)c | ((unsigned)f16b(w) << 16);
        }
    }
}

// ---------------- sparse prop (pure gather: hout = L_hat @ hin), 16B lanes ----------------
// UNCHANGED from round 8 (proven). 1 wave per node; 4 edges per wave-load via
// quarter-wave split: lane = e2(2b) x s(4b 16B segment). 6 dwordx4 loads =
// 24 edge-slots/iter. Metadata via 4 wave-uniform scalar loads + cndmask.
__global__ __launch_bounds__(256) void prop_f16_kernel(
    const uint4* __restrict__ hin4, uint4* __restrict__ hout4,
    const int* __restrict__ row_ptr, const unsigned* __restrict__ e_cw, int n)
{
    int wv = __builtin_amdgcn_readfirstlane(threadIdx.x >> 6);
    int node = blockIdx.x * 4 + wv;
    if (node >= n) return;
    const int lane = threadIdx.x & 63;
    const int e2 = lane >> 4;      // edge within 4-pack (0..3)
    const int s = lane & 15;       // 16B segment (features 8s..8s+7)
    int rs = row_ptr[node];
    int re = row_ptr[node + 1];

    h2 a0 = {(_Float16)0.f, (_Float16)0.f};
    h2 a1 = {(_Float16)0.f, (_Float16)0.f};
    h2 a2 = {(_Float16)0.f, (_Float16)0.f};
    h2 a3 = {(_Float16)0.f, (_Float16)0.f};

    for (int j = rs; j < re; j += 24) {
        uint4 vv[6]; unsigned ww[6];
        #pragma unroll
        for (int u = 0; u < 6; ++u) {
            int i0 = j + 4 * u;
            unsigned c0 = (i0     < re) ? e_cw[i0]     : 0u;   // uniform -> s_load/s_cselect
            unsigned c1 = (i0 + 1 < re) ? e_cw[i0 + 1] : 0u;
            unsigned c2 = (i0 + 2 < re) ? e_cw[i0 + 2] : 0u;
            unsigned c3 = (i0 + 3 < re) ? e_cw[i0 + 3] : 0u;
            unsigned cw = (e2 == 0) ? c0 : (e2 == 1) ? c1 : (e2 == 2) ? c2 : c3;
            ww[u] = (cw & 0xffff0000u) | (cw >> 16);           // (w,w) packed f16 pair
            vv[u] = hin4[(size_t)(cw & 0xffffu) * 16 + s];
        }
        #pragma unroll
        for (int u = 0; u < 6; ++u) {
            h2 wp = f2h(__uint_as_float(ww[u]));
            a0 = f2h(__uint_as_float(vv[u].x)) * wp + a0;      // v_pk_fma_f16
            a1 = f2h(__uint_as_float(vv[u].y)) * wp + a1;
            a2 = f2h(__uint_as_float(vv[u].z)) * wp + a2;
            a3 = f2h(__uint_as_float(vv[u].w)) * wp + a3;
        }
    }
    // reduce across the 4 edge-quarters (lane bits 4,5)
    #pragma unroll
    for (int off = 16; off < 64; off <<= 1) {
        a0 = a0 + f2h(__shfl_xor(h2f(a0), off));
        a1 = a1 + f2h(__shfl_xor(h2f(a1), off));
        a2 = a2 + f2h(__shfl_xor(h2f(a2), off));
        a3 = a3 + f2h(__shfl_xor(h2f(a3), off));
    }

    if (e2 == 0) {
        uint4 o;
        o.x = __float_as_uint(h2f(a0));
        o.y = __float_as_uint(h2f(a1));
        o.z = __float_as_uint(h2f(a2));
        o.w = __float_as_uint(h2f(a3));
        hout4[(size_t)node * 16 + s] = o;
    }
}

// ---------------- fused 3-way MFMA GEMM (f16) + bias + ReLU (unchanged, r8) ----------------
#define WPAD 136
__global__ __launch_bounds__(256) void gemm3_mfma_kernel(
    const unsigned short* __restrict__ X0, const unsigned short* __restrict__ X1,
    const unsigned short* __restrict__ X2,
    const unsigned short* __restrict__ Wt, const float* __restrict__ bias,
    void* __restrict__ out, int n, int out_f16)
{
    __shared__ unsigned short Ws[DFEAT * WPAD];   // 34816 B
    const int t    = threadIdx.x;
    const int wave = t >> 6;
    const int lane = t & 63;
    const int quad = lane >> 4;
    const int l16  = lane & 15;

    const int row_base = blockIdx.x * 128 + wave * 32;
    int r0 = row_base + l16;       if (r0 >= n) r0 = n - 1;
    int r1 = row_base + 16 + l16;  if (r1 >= n) r1 = n - 1;

    const unsigned short* Xps[3] = {X0, X1, X2};

    f32x4 acc[2][8];
    #pragma unroll
    for (int tt = 0; tt < 2; ++tt)
        #pragma unroll
        for (int c = 0; c < 8; ++c) acc[tt][c] = (f32x4){0.f, 0.f, 0.f, 0.f};

    const int srow = t >> 1;            // staging: row 0..127
    const int shalf = (t & 1) * 64;     // half-row

    #pragma unroll
    for (int seg = 0; seg < 3; ++seg) {
        __syncthreads();   // previous seg fully consumed
        const unsigned short* Wp = Wt + (seg << 14);
        #pragma unroll
        for (int i = 0; i < 8; ++i) {
            *(u16x8*)&Ws[srow * WPAD + shalf + i * 8] =
                *(const u16x8*)&Wp[srow * DFEAT + shalf + i * 8];
        }
        __syncthreads();
        const unsigned short* A0 = Xps[seg] + (size_t)r0 * DFEAT;
        const unsigned short* A1 = Xps[seg] + (size_t)r1 * DFEAT;
        #pragma unroll
        for (int kk = 0; kk < 4; ++kk) {
            const int ko = kk * 32 + quad * 8;
            f16x8 a0 = *(const f16x8*)(A0 + ko);
            f16x8 a1 = *(const f16x8*)(A1 + ko);
            #pragma unroll
            for (int c = 0; c < 8; ++c) {
                f16x8 b = *(const f16x8*)&Ws[(c * 16 + l16) * WPAD + ko];
                acc[0][c] = __builtin_amdgcn_mfma_f32_16x16x32_f16(a0, b, acc[0][c], 0, 0, 0);
                acc[1][c] = __builtin_amdgcn_mfma_f32_16x16x32_f16(a1, b, acc[1][c], 0, 0, 0);
            }
        }
    }

    // C/D layout: col = lane&15, row = quad*4 + reg
    #pragma unroll
    for (int tt = 0; tt < 2; ++tt) {
        int orow0 = blockIdx.x * 128 + wave * 32 + tt * 16 + quad * 4;
        #pragma unroll
        for (int c = 0; c < 8; ++c) {
            int col = c * 16 + l16;
            float bv = bias[col];
            #pragma unroll
            for (int r = 0; r < 4; ++r) {
                int orow = orow0 + r;
                if (orow < n) {
                    float v = fmaxf(acc[tt][c][r] + bv, 0.f);
                    if (out_f16)
                        ((unsigned short*)out)[(size_t)orow * DFEAT + col] = f16b(v);
                    else
                        ((float*)out)[(size_t)orow * DFEAT + col] = v;
                }
            }
        }
    }
}

extern "C" void kernel_launch(void* const* d_in, const int* in_sizes, int n_in,
                              void* d_out, int out_size, void* d_ws, size_t ws_size,
                              hipStream_t stream) {
    const float* x  = (const float*)d_in[0];
    const int*   ei = (const int*)d_in[1];
    const float* W1 = (const float*)d_in[2];
    const float* b1 = (const float*)d_in[3];
    const float* W2 = (const float*)d_in[4];
    const float* b2 = (const float*)d_in[5];
    const float* W3 = (const float*)d_in[6];
    const float* b3 = (const float*)d_in[7];

    int N = in_sizes[0] / DFEAT;   // 50000
    int E = in_sizes[1] / 2;       // 800000
    const int NPK = N * (DFEAT / 2);     // packed f16x2 words per array

    // workspace layout
    unsigned* xb  = (unsigned*)d_ws;
    unsigned* t1b = xb  + NPK;
    unsigned* t2b = t1b + NPK;
    unsigned* ab  = t2b + NPK;
    unsigned short* wt = (unsigned short*)(ab + NPK);   // 3 layers * 3*128*128
    int*   deg8    = (int*)(wt + 3 * 3 * DFEAT * DFEAT);
    int*   poff    = deg8 + 8 * N;
    int*   row_ptr = poff + 8 * N;
    float* dinv    = (float*)(row_ptr + (N + 2));
    unsigned* e_cw = (unsigned*)(dinv + N);
    int*   csum    = (int*)(e_cw + E);                  // (N+63)/64 entries

    const float2* x2 = (const float2*)x;

    static int prep_blocks = 0;
    if (prep_blocks == 0) {
        int nb = 0;
        hipOccupancyMaxActiveBlocksPerMultiprocessor(&nb, (const void*)prep_mega_kernel, 256, 0);
        if (nb < 1) nb = 1;
        long g = (long)nb * 256;           // 256 CUs on MI355X
        prep_blocks = (int)((g > 2048) ? 2048 : g);
    }

    void* args[] = {
        (void*)&x2, (void*)&ei,
        (void*)&W1, (void*)&W2, (void*)&W3,
        (void*)&xb, (void*)&wt, (void*)&deg8, (void*)&poff,
        (void*)&row_ptr, (void*)&dinv, (void*)&e_cw, (void*)&csum,
        (void*)&N, (void*)&E
    };
    hipLaunchCooperativeKernel((const void*)prep_mega_kernel,
                               dim3(prep_blocks), dim3(256), args, 0, stream);

    const float* bl[3] = {b1, b2, b3};
    const int WELEM = 3 * DFEAT * DFEAT;
    const unsigned* hin = xb;
    const int prop_grid = (N + 3) / 4;
    const int gemm_grid = (N + 127) / 128;
    for (int l = 0; l < 3; ++l) {
        // Tx1 = L_hat @ h
        prop_f16_kernel<<<prop_grid, 256, 0, stream>>>(
            (const uint4*)hin, (uint4*)t1b, row_ptr, e_cw, N);
        // P = L_hat @ Tx1   (2P - h folded into weights)
        prop_f16_kernel<<<prop_grid, 256, 0, stream>>>(
            (const uint4*)t1b, (uint4*)t2b, row_ptr, e_cw, N);
        // out = relu(h@(W0-W2) + Tx1@W1 + P@(2W2) + b)
        void* hout = (l == 2) ? d_out : (void*)ab;
        gemm3_mfma_kernel<<<gemm_grid, 256, 0, stream>>>(
            (const unsigned short*)hin, (const unsigned short*)t1b, (const unsigned short*)t2b,
            wt + l * WELEM, bl[l], hout, N, (l == 2) ? 0 : 1);
        hin = ab;
    }
}

// Round 12
// 997.318 us; speedup vs baseline: 1.0249x; 1.0249x over previous
//
#include <hip/hip_runtime.h>
#include <hip/hip_bf16.h>

#define DFEAT 128

typedef _Float16 h2 __attribute__((ext_vector_type(2)));
typedef _Float16 f16x8 __attribute__((ext_vector_type(8)));
typedef float f32x4  __attribute__((ext_vector_type(4)));
typedef unsigned short u16x8 __attribute__((ext_vector_type(8)));

__device__ __forceinline__ unsigned short f16b(float f) {
    _Float16 hf = (_Float16)f;
    unsigned short b; __builtin_memcpy(&b, &hf, 2);
    return b;
}
__device__ __forceinline__ unsigned pack_f16(float lo, float hi) {
    return (unsigned)f16b(lo) | ((unsigned)f16b(hi) << 16);
}
__device__ __forceinline__ float h2f(h2 v) { float f; __builtin_memcpy(&f, &v, 4); return f; }
__device__ __forceinline__ h2 f2h(float f) { h2 v; __builtin_memcpy(&v, &f, 4); return v; }

// Chebyshev algebra folded into weights (fp32, at prep):
//   out = h@(W0 - W2) + Tx1@W1 + P@(2*W2),  P = L_hat @ Tx1
// -> both props are identical pure gathers.
//
// r11 lesson: hipLaunchCooperativeKernel grid.sync is pathological on this
// chip (1042us for 45us of work, VALUBusy 0.4% -> waves asleep in sync).
// r12: same verified phases, HAND-ROLLED persistent barrier at 1024 blocks
// (4/CU, 2x under the >=8/CU residency capacity at VGPR<=128 -> all blocks
// co-resident without preemption). Counter zeroed via hipMemsetAsync
// (graph-capture-legal). Props/GEMMs unchanged from the proven r8 (389us).

#define PREP_BLOCKS 1024

__device__ __forceinline__ void gbar(int* cnt, int target) {
    __syncthreads();
    if (threadIdx.x == 0) {
        __threadfence();                          // agent-scope release
        atomicAdd(cnt, 1);                        // device-scope (m20)
        while (__hip_atomic_load(cnt, __ATOMIC_ACQUIRE, __HIP_MEMORY_SCOPE_AGENT) < target) {
            __builtin_amdgcn_s_sleep(2);
        }
        __threadfence();                          // agent-scope acquire fence
    }
    __syncthreads();
}

// ---------------- persistent preprocessing kernel (phases verified in r9/r11) ----------------
// P0 pack x->f16 + fold W + zero deg8 | P1 degree count | P2 64-chunk scan
// P3 1-wave csum scan | P4 final row_ptr | P5 CSR fill
__global__ __launch_bounds__(256, 4) void prep_persist_kernel(
    const float2* __restrict__ x2, const int* __restrict__ ei,
    const float* __restrict__ W1, const float* __restrict__ W2,
    const float* __restrict__ W3,
    unsigned* __restrict__ xb, unsigned short* __restrict__ wt,
    int* __restrict__ deg8, int* __restrict__ poff,
    int* __restrict__ row_ptr, float* __restrict__ dinv,
    unsigned* __restrict__ e_cw, int* __restrict__ csum,
    int* __restrict__ bar, int N, int E)
{
    const int t = threadIdx.x;
    const int tid = blockIdx.x * 256 + t;
    const int nthreads = gridDim.x * 256;
    const int lane = t & 63;

    // ---- P0: zero deg8 + pack x -> f16 + fold W -> transposed f16 ----
    const int NPK = N * (DFEAT / 2);
    for (int i = tid; i < 8 * N; i += nthreads) deg8[i] = 0;
    for (int i = tid; i < NPK; i += nthreads) {
        float2 v = x2[i];
        xb[i] = pack_f16(v.x, v.y);
    }
    const int PER = 3 * DFEAT * DFEAT;
    for (int i = tid; i < 3 * PER; i += nthreads) {
        int layer = i / PER;
        int rem = i - layer * PER;
        const float* W = (layer == 0) ? W1 : ((layer == 1) ? W2 : W3);
        int seg = rem >> 14;
        int k   = (rem >> 7) & 127;
        int nn  = rem & 127;
        float w = W[rem];
        if (seg == 0) w -= W[rem + 2 * DFEAT * DFEAT];   // W0' = W0 - W2
        else if (seg == 2) w *= 2.f;                      // W2' = 2*W2
        wt[layer * PER + (seg << 14) + (nn << 7) + k] = f16b(w);
    }
    gbar(bar, 1 * gridDim.x);

    // ---- P1: degree count (edge-index-partitioned atomics) ----
    for (int e = tid; e < E; e += nthreads) {
        int r = ei[e];
        int c = ei[E + e];
        if (r != c) atomicAdd(&deg8[((e >> 8) & 7) * N + r], 1);
    }
    gbar(bar, 2 * gridDim.x);

    // ---- P2: per-64-node chunks: poff, dinv, chunk-local scan, chunk totals ----
    const int NCH = (N + 63) / 64;
    const int gwave = tid >> 6;
    const int ngwave = nthreads >> 6;
    for (int w = gwave; w < NCH; w += ngwave) {
        int node = w * 64 + lane;
        int tot = 0;
        if (node < N) {
            int run = 0;
            #pragma unroll
            for (int p = 0; p < 8; ++p) {
                int d = deg8[p * N + node];
                poff[p * N + node] = run;   // partition start; doubles as fill cursor
                run += d;
            }
            tot = run;
            dinv[node] = (tot > 0) ? rsqrtf((float)tot) : 0.f;
        }
        int vi = tot;
        #pragma unroll
        for (int off = 1; off < 64; off <<= 1) {
            int xx = __shfl_up(vi, off);
            if (lane >= off) vi += xx;
        }
        if (node < N) row_ptr[node + 1] = vi;   // chunk-local inclusive prefix
        if (lane == 63) csum[w] = vi;           // chunk total
    }
    gbar(bar, 3 * gridDim.x);

    // ---- P3: exclusive scan of chunk totals (one wave) ----
    if (blockIdx.x == 0 && t < 64) {
        int carry = 0;
        for (int base = 0; base < NCH; base += 64) {
            int v = (base + t < NCH) ? csum[base + t] : 0;
            int vi = v;
            #pragma unroll
            for (int off = 1; off < 64; off <<= 1) {
                int xx = __shfl_up(vi, off);
                if (t >= off) vi += xx;
            }
            if (base + t < NCH) csum[base + t] = carry + vi - v;
            carry += __shfl(vi, 63);
        }
    }
    gbar(bar, 4 * gridDim.x);

    // ---- P4: add chunk offsets -> final row_ptr ----
    for (int i = tid; i < N; i += nthreads) {
        if (i == 0) row_ptr[0] = 0;
        row_ptr[i + 1] += csum[i >> 6];
    }
    gbar(bar, 5 * gridDim.x);

    // ---- P5: CSR fill (col:u16 | w:f16) ----
    for (int e = tid; e < E; e += nthreads) {
        int r = ei[e];
        int c = ei[E + e];
        if (r != c) {
            int p = (e >> 8) & 7;   // must match P1 partitioning
            int k = atomicAdd(&poff[p * N + r], 1);
            int pos = row_ptr[r] + k;
            float w = -dinv[r] * dinv[c];
            e_cw[pos] = (unsigned)c | ((unsigned)f16b(w) << 16);
        }
    }
}

// ---------------- sparse prop (pure gather: hout = L_hat @ hin), 16B lanes ----------------
// UNCHANGED from round 8 (proven). 1 wave per node; 4 edges per wave-load via
// quarter-wave split: lane = e2(2b) x s(4b 16B segment). 6 dwordx4 loads =
// 24 edge-slots/iter. Metadata via 4 wave-uniform scalar loads + cndmask.
__global__ __launch_bounds__(256) void prop_f16_kernel(
    const uint4* __restrict__ hin4, uint4* __restrict__ hout4,
    const int* __restrict__ row_ptr, const unsigned* __restrict__ e_cw, int n)
{
    int wv = __builtin_amdgcn_readfirstlane(threadIdx.x >> 6);
    int node = blockIdx.x * 4 + wv;
    if (node >= n) return;
    const int lane = threadIdx.x & 63;
    const int e2 = lane >> 4;      // edge within 4-pack (0..3)
    const int s = lane & 15;       // 16B segment (features 8s..8s+7)
    int rs = row_ptr[node];
    int re = row_ptr[node + 1];

    h2 a0 = {(_Float16)0.f, (_Float16)0.f};
    h2 a1 = {(_Float16)0.f, (_Float16)0.f};
    h2 a2 = {(_Float16)0.f, (_Float16)0.f};
    h2 a3 = {(_Float16)0.f, (_Float16)0.f};

    for (int j = rs; j < re; j += 24) {
        uint4 vv[6]; unsigned ww[6];
        #pragma unroll
        for (int u = 0; u < 6; ++u) {
            int i0 = j + 4 * u;
            unsigned c0 = (i0     < re) ? e_cw[i0]     : 0u;   // uniform -> s_load/s_cselect
            unsigned c1 = (i0 + 1 < re) ? e_cw[i0 + 1] : 0u;
            unsigned c2 = (i0 + 2 < re) ? e_cw[i0 + 2] : 0u;
            unsigned c3 = (i0 + 3 < re) ? e_cw[i0 + 3] : 0u;
            unsigned cw = (e2 == 0) ? c0 : (e2 == 1) ? c1 : (e2 == 2) ? c2 : c3;
            ww[u] = (cw & 0xffff0000u) | (cw >> 16);           // (w,w) packed f16 pair
            vv[u] = hin4[(size_t)(cw & 0xffffu) * 16 + s];
        }
        #pragma unroll
        for (int u = 0; u < 6; ++u) {
            h2 wp = f2h(__uint_as_float(ww[u]));
            a0 = f2h(__uint_as_float(vv[u].x)) * wp + a0;      // v_pk_fma_f16
            a1 = f2h(__uint_as_float(vv[u].y)) * wp + a1;
            a2 = f2h(__uint_as_float(vv[u].z)) * wp + a2;
            a3 = f2h(__uint_as_float(vv[u].w)) * wp + a3;
        }
    }
    // reduce across the 4 edge-quarters (lane bits 4,5)
    #pragma unroll
    for (int off = 16; off < 64; off <<= 1) {
        a0 = a0 + f2h(__shfl_xor(h2f(a0), off));
        a1 = a1 + f2h(__shfl_xor(h2f(a1), off));
        a2 = a2 + f2h(__shfl_xor(h2f(a2), off));
        a3 = a3 + f2h(__shfl_xor(h2f(a3), off));
    }

    if (e2 == 0) {
        uint4 o;
        o.x = __float_as_uint(h2f(a0));
        o.y = __float_as_uint(h2f(a1));
        o.z = __float_as_uint(h2f(a2));
        o.w = __float_as_uint(h2f(a3));
        hout4[(size_t)node * 16 + s] = o;
    }
}

// ---------------- fused 3-way MFMA GEMM (f16) + bias + ReLU (unchanged, r8) ----------------
#define WPAD 136
__global__ __launch_bounds__(256) void gemm3_mfma_kernel(
    const unsigned short* __restrict__ X0, const unsigned short* __restrict__ X1,
    const unsigned short* __restrict__ X2,
    const unsigned short* __restrict__ Wt, const float* __restrict__ bias,
    void* __restrict__ out, int n, int out_f16)
{
    __shared__ unsigned short Ws[DFEAT * WPAD];   // 34816 B
    const int t    = threadIdx.x;
    const int wave = t >> 6;
    const int lane = t & 63;
    const int quad = lane >> 4;
    const int l16  = lane & 15;

    const int row_base = blockIdx.x * 128 + wave * 32;
    int r0 = row_base + l16;       if (r0 >= n) r0 = n - 1;
    int r1 = row_base + 16 + l16;  if (r1 >= n) r1 = n - 1;

    const unsigned short* Xps[3] = {X0, X1, X2};

    f32x4 acc[2][8];
    #pragma unroll
    for (int tt = 0; tt < 2; ++tt)
        #pragma unroll
        for (int c = 0; c < 8; ++c) acc[tt][c] = (f32x4){0.f, 0.f, 0.f, 0.f};

    const int srow = t >> 1;            // staging: row 0..127
    const int shalf = (t & 1) * 64;     // half-row

    #pragma unroll
    for (int seg = 0; seg < 3; ++seg) {
        __syncthreads();   // previous seg fully consumed
        const unsigned short* Wp = Wt + (seg << 14);
        #pragma unroll
        for (int i = 0; i < 8; ++i) {
            *(u16x8*)&Ws[srow * WPAD + shalf + i * 8] =
                *(const u16x8*)&Wp[srow * DFEAT + shalf + i * 8];
        }
        __syncthreads();
        const unsigned short* A0 = Xps[seg] + (size_t)r0 * DFEAT;
        const unsigned short* A1 = Xps[seg] + (size_t)r1 * DFEAT;
        #pragma unroll
        for (int kk = 0; kk < 4; ++kk) {
            const int ko = kk * 32 + quad * 8;
            f16x8 a0 = *(const f16x8*)(A0 + ko);
            f16x8 a1 = *(const f16x8*)(A1 + ko);
            #pragma unroll
            for (int c = 0; c < 8; ++c) {
                f16x8 b = *(const f16x8*)&Ws[(c * 16 + l16) * WPAD + ko];
                acc[0][c] = __builtin_amdgcn_mfma_f32_16x16x32_f16(a0, b, acc[0][c], 0, 0, 0);
                acc[1][c] = __builtin_amdgcn_mfma_f32_16x16x32_f16(a1, b, acc[1][c], 0, 0, 0);
            }
        }
    }

    // C/D layout: col = lane&15, row = quad*4 + reg
    #pragma unroll
    for (int tt = 0; tt < 2; ++tt) {
        int orow0 = blockIdx.x * 128 + wave * 32 + tt * 16 + quad * 4;
        #pragma unroll
        for (int c = 0; c < 8; ++c) {
            int col = c * 16 + l16;
            float bv = bias[col];
            #pragma unroll
            for (int r = 0; r < 4; ++r) {
                int orow = orow0 + r;
                if (orow < n) {
                    float v = fmaxf(acc[tt][c][r] + bv, 0.f);
                    if (out_f16)
                        ((unsigned short*)out)[(size_t)orow * DFEAT + col] = f16b(v);
                    else
                        ((float*)out)[(size_t)orow * DFEAT + col] = v;
                }
            }
        }
    }
}

extern "C" void kernel_launch(void* const* d_in, const int* in_sizes, int n_in,
                              void* d_out, int out_size, void* d_ws, size_t ws_size,
                              hipStream_t stream) {
    const float* x  = (const float*)d_in[0];
    const int*   ei = (const int*)d_in[1];
    const float* W1 = (const float*)d_in[2];
    const float* b1 = (const float*)d_in[3];
    const float* W2 = (const float*)d_in[4];
    const float* b2 = (const float*)d_in[5];
    const float* W3 = (const float*)d_in[6];
    const float* b3 = (const float*)d_in[7];

    const int N = in_sizes[0] / DFEAT;   // 50000
    const int E = in_sizes[1] / 2;       // 800000
    const int NPK = N * (DFEAT / 2);     // packed f16x2 words per array

    // workspace layout
    unsigned* xb  = (unsigned*)d_ws;
    unsigned* t1b = xb  + NPK;
    unsigned* t2b = t1b + NPK;
    unsigned* ab  = t2b + NPK;
    unsigned short* wt = (unsigned short*)(ab + NPK);   // 3 layers * 3*128*128
    int*   deg8    = (int*)(wt + 3 * 3 * DFEAT * DFEAT);
    int*   poff    = deg8 + 8 * N;
    int*   row_ptr = poff + 8 * N;
    float* dinv    = (float*)(row_ptr + (N + 2));
    unsigned* e_cw = (unsigned*)(dinv + N);
    int*   csum    = (int*)(e_cw + E);                  // (N+63)/64 entries
    int*   bar     = csum + ((N + 63) / 64) + 1;        // persistent barrier counter

    hipMemsetAsync(bar, 0, sizeof(int), stream);

    const float2* x2 = (const float2*)x;
    prep_persist_kernel<<<PREP_BLOCKS, 256, 0, stream>>>(
        x2, ei, W1, W2, W3, xb, wt, deg8, poff, row_ptr, dinv, e_cw, csum, bar, N, E);

    const float* bl[3] = {b1, b2, b3};
    const int WELEM = 3 * DFEAT * DFEAT;
    const unsigned* hin = xb;
    const int prop_grid = (N + 3) / 4;
    const int gemm_grid = (N + 127) / 128;
    for (int l = 0; l < 3; ++l) {
        // Tx1 = L_hat @ h
        prop_f16_kernel<<<prop_grid, 256, 0, stream>>>(
            (const uint4*)hin, (uint4*)t1b, row_ptr, e_cw, N);
        // P = L_hat @ Tx1   (2P - h folded into weights)
        prop_f16_kernel<<<prop_grid, 256, 0, stream>>>(
            (const uint4*)t1b, (uint4*)t2b, row_ptr, e_cw, N);
        // out = relu(h@(W0-W2) + Tx1@W1 + P@(2W2) + b)
        void* hout = (l == 2) ? d_out : (void*)ab;
        gemm3_mfma_kernel<<<gemm_grid, 256, 0, stream>>>(
            (const unsigned short*)hin, (const unsigned short*)t1b, (const unsigned short*)t2b,
            wt + l * WELEM, bl[l], hout, N, (l == 2) ? 0 : 1);
        hin = ab;
    }
}